// Round 1
// baseline (1060.808 us; speedup 1.0000x reference)
//
#include <hip/hip_runtime.h>

typedef unsigned short u16;
typedef unsigned int   u32;
using bf16x8 = __attribute__((ext_vector_type(8))) __bf16;
using f32x4  = __attribute__((ext_vector_type(4))) float;

// B=2, S=2048, D=4096, H=32, KV=8, HD=128 hardcoded throughout.

__device__ __forceinline__ u16 f2bf(float f) {
  u32 u = __builtin_bit_cast(u32, f);
  return (u16)((u + 0x7fffu + ((u >> 16) & 1u)) >> 16);
}
__device__ __forceinline__ float bf2f(u16 h) {
  return __builtin_bit_cast(float, (u32)h << 16);
}
__device__ __forceinline__ f32x4 mfma16(bf16x8 a, bf16x8 b, f32x4 c) {
  return __builtin_amdgcn_mfma_f32_16x16x32_bf16(a, b, c, 0, 0, 0);
}
__device__ __forceinline__ void g2l16(const void* gp, void* lp) {
  __builtin_amdgcn_global_load_lds(
      (__attribute__((address_space(1))) void*)(void*)gp,
      (__attribute__((address_space(3))) void*)lp, 16, 0, 0);
}

// ---------------- fp32 -> bf16 elementwise ----------------
__global__ void k_cvt(const float* __restrict__ in, u16* __restrict__ out, int n4) {
  int i = blockIdx.x * 256 + threadIdx.x;
  if (i >= n4) return;
  float4 v = ((const float4*)in)[i];
  ushort4 o;
  o.x = f2bf(v.x); o.y = f2bf(v.y); o.z = f2bf(v.z); o.w = f2bf(v.w);
  ((ushort4*)out)[i] = o;
}

// ---------------- fp32 (K,N) -> bf16 (N,K) transpose-convert ----------------
__global__ void k_tcvt(const float* __restrict__ in, u16* __restrict__ out, int K, int N) {
  __shared__ u16 t[32][33];
  int n0 = blockIdx.x * 32, k0 = blockIdx.y * 32;
  int r = threadIdx.x >> 3, c4 = (threadIdx.x & 7) * 4;
  float4 v = *(const float4*)(in + (size_t)(k0 + r) * N + n0 + c4);
  t[c4 + 0][r] = f2bf(v.x);
  t[c4 + 1][r] = f2bf(v.y);
  t[c4 + 2][r] = f2bf(v.z);
  t[c4 + 3][r] = f2bf(v.w);
  __syncthreads();
  ushort4 o;
  o.x = t[r][c4 + 0]; o.y = t[r][c4 + 1]; o.z = t[r][c4 + 2]; o.w = t[r][c4 + 3];
  *(ushort4*)(out + (size_t)(n0 + r) * K + k0 + c4) = o;
}

// ---------------- 128x128x32 bf16 GEMM (m97 structure) ----------------
// A: (M,K) bf16 row-major.  Bt: (N,K) bf16 row-major (pre-transposed).
// MODE 1: bf16 out relayout (b, NH, s, d), row=(b,s) col=(h,d)
// MODE 2: fp32 out plain row-major
// MODE 3: bf16 out 4-way split (K0|K1|V0|V1), each (b,8,s,d)
template <int MODE>
__global__ __launch_bounds__(256) void k_gemm(const u16* __restrict__ A, const u16* __restrict__ Bt,
                                              void* __restrict__ Cp, int M, int N, int K, int NH) {
  __shared__ u16 As[128 * 32];
  __shared__ u16 Bs[128 * 32];
  const int m0 = blockIdx.y * 128, n0 = blockIdx.x * 128;
  const int tid = threadIdx.x, wid = tid >> 6, l = tid & 63, g = l >> 4, li = l & 15;
  const int rb = (wid >> 1) * 64, cb = (wid & 1) * 64;
  const f32x4 vzero = {0.f, 0.f, 0.f, 0.f};
  f32x4 acc[4][4];
  for (int m = 0; m < 4; ++m)
    for (int n = 0; n < 4; ++n) acc[m][n] = vzero;
  const int srow = l >> 2, scol = (l & 3) * 8;  // staging: 8KB tile = 8 chunks of 1KB
  for (int k0 = 0; k0 < K; k0 += 32) {
#pragma unroll
    for (int i = 0; i < 2; ++i) {
      int c = wid * 2 + i;
      g2l16(A + (size_t)(m0 + c * 16 + srow) * K + k0 + scol, As + c * 512);
      g2l16(Bt + (size_t)(n0 + c * 16 + srow) * K + k0 + scol, Bs + c * 512);
    }
    __syncthreads();
    bf16x8 af[4], bf[4];
#pragma unroll
    for (int m = 0; m < 4; ++m) af[m] = *(const bf16x8*)(As + (rb + m * 16 + li) * 32 + g * 8);
#pragma unroll
    for (int n = 0; n < 4; ++n) bf[n] = *(const bf16x8*)(Bs + (cb + n * 16 + li) * 32 + g * 8);
#pragma unroll
    for (int m = 0; m < 4; ++m)
#pragma unroll
      for (int n = 0; n < 4; ++n)
        acc[m][n] = mfma16(af[m], bf[n], acc[m][n]);
    __syncthreads();
  }
  (void)NH;
#pragma unroll
  for (int m = 0; m < 4; ++m)
#pragma unroll
    for (int n = 0; n < 4; ++n)
#pragma unroll
      for (int j = 0; j < 4; ++j) {
        int row = m0 + rb + m * 16 + g * 4 + j;   // C/D: row=(l>>4)*4+reg
        int col = n0 + cb + n * 16 + li;          //      col=l&15
        float v = acc[m][n][j];
        if constexpr (MODE == 2) {
          ((float*)Cp)[(size_t)row * N + col] = v;
        } else if constexpr (MODE == 1) {
          int b = row >> 11, s = row & 2047, h = col >> 7, d = col & 127;
          ((u16*)Cp)[(((size_t)(b * NH + h)) * 2048 + s) * 128 + d] = f2bf(v);
        } else {
          int b = row >> 11, s = row & 2047;
          int buf = col >> 10, hh = (col >> 7) & 7, d = col & 127;
          ((u16*)Cp)[(size_t)buf * 4194304 + (((size_t)(b * 8 + hh)) * 2048 + s) * 128 + d] = f2bf(v);
        }
      }
}

// ---------------- RoPE on Q in place, fused 1/sqrt(128) scale ----------------
// Qr layout (b,h,s,d); one wave per row; lane l handles pair (d=l, d=l+64).
__global__ void k_ropeq(u16* __restrict__ Q, const int* __restrict__ pos) {
  int row = blockIdx.x * 4 + (threadIdx.x >> 6);
  int l = threadIdx.x & 63;
  int s = row & 2047;
  u16* p = Q + (size_t)row * 128;
  float x1 = bf2f(p[l]), x2 = bf2f(p[l + 64]);
  float ang = (float)pos[s] * expf((float)l * -0.14391156831212787f);  // ln(1e4)/64
  float cs = cosf(ang), sn = sinf(ang);
  const float sc = 0.08838834764831845f;  // 1/sqrt(128)
  p[l] = f2bf((x1 * cs - x2 * sn) * sc);
  p[l + 64] = f2bf((x2 * cs + x1 * sn) * sc);
}

// ---------------- K/V: modality select + RoPE(K) + V transpose to (d,s) ----------------
// block = (b, kv, 64-token tile); K0..V1 are (b,8,s,d) bf16.
__global__ void k_kvprep(const u16* __restrict__ K0, const u16* __restrict__ K1,
                         const u16* __restrict__ V0, const u16* __restrict__ V1,
                         const int* __restrict__ mod, const int* __restrict__ pos,
                         u16* __restrict__ Kr, u16* __restrict__ Vt) {
  __shared__ u16 Vl[64][136];
  int blk = blockIdx.x;
  int st = blk & 31, kvh = (blk >> 5) & 7, b = blk >> 8;
  int s0 = st * 64;
  int tid = threadIdx.x, wid = tid >> 6, l = tid & 63;
  float invf = expf((float)l * -0.14391156831212787f);
  size_t slab = (size_t)(b * 8 + kvh) * 2048;
  for (int rr = 0; rr < 16; ++rr) {
    int r = wid * 16 + rr;
    int s = s0 + r;
    int sel = mod[b * 2048 + s];
    const u16* ks = (sel ? K1 : K0) + (slab + s) * 128;
    const u16* vs = (sel ? V1 : V0) + (slab + s) * 128;
    float ang = (float)pos[s] * invf;
    float cs = cosf(ang), sn = sinf(ang);
    float x1 = bf2f(ks[l]), x2 = bf2f(ks[l + 64]);
    u16* kd = Kr + (slab + s) * 128;
    kd[l] = f2bf(x1 * cs - x2 * sn);
    kd[l + 64] = f2bf(x2 * cs + x1 * sn);
    Vl[r][l] = vs[l];
    Vl[r][l + 64] = vs[l + 64];
  }
  __syncthreads();
  int d = tid >> 1, si0 = (tid & 1) * 32;
  u16* vd = Vt + ((size_t)(b * 8 + kvh) * 128 + d) * 2048 + s0 + si0;
#pragma unroll
  for (int k4 = 0; k4 < 8; ++k4) {
    ushort4 o;
    o.x = Vl[si0 + k4 * 4 + 0][d];
    o.y = Vl[si0 + k4 * 4 + 1][d];
    o.z = Vl[si0 + k4 * 4 + 2][d];
    o.w = Vl[si0 + k4 * 4 + 3][d];
    *(ushort4*)(vd + k4 * 4) = o;
  }
}

// ---------------- causal GQA flash attention ----------------
// grid (S/64, B*H).  4 waves; wave owns 16 q-rows.  KBLK=64.
// K staged (64 rows x 256B) and Vt staged (128 rows x 128B) with
// inverse-swizzled global src + XOR-swizzled ds_read (rule #21).
__global__ __launch_bounds__(256) void k_attn(const u16* __restrict__ Q, const u16* __restrict__ Kr,
                                              const u16* __restrict__ Vt, u16* __restrict__ ctx) {
  __shared__ u16 Kl[64 * 128];
  __shared__ u16 Vl[128 * 64];
  __shared__ __bf16 Pl[4][16 * 72];
  const int qt = blockIdx.x, bh = blockIdx.y;
  const int b = bh >> 5, h = bh & 31, kvh = h >> 2;
  const int tid = threadIdx.x, wid = tid >> 6, l = tid & 63, g = l >> 4, li = l & 15;
  const int q0 = qt * 64;
  const size_t kvslab = (size_t)(b * 8 + kvh) * 2048;
  // Q fragments (already RoPE'd + scaled): A-map (l,j) -> row=li, k=g*8+j
  const u16* qrow = Q + ((size_t)bh * 2048 + q0 + wid * 16 + li) * 128;
  bf16x8 qf[4];
#pragma unroll
  for (int ks = 0; ks < 4; ++ks) qf[ks] = *(const bf16x8*)(qrow + ks * 32 + g * 8);
  const f32x4 vzero = {0.f, 0.f, 0.f, 0.f};
  f32x4 o[8];
#pragma unroll
  for (int i = 0; i < 8; ++i) o[i] = vzero;
  float mrow[4] = {-1e30f, -1e30f, -1e30f, -1e30f};
  float lsum[4] = {0.f, 0.f, 0.f, 0.f};
  const u16* Kg = Kr + kvslab * 128;
  const u16* Vg = Vt + kvslab * 128;  // (d, s) layout

  for (int kt = 0; kt <= qt; ++kt) {
#pragma unroll
    for (int i = 0; i < 4; ++i) {
      int c = wid * 4 + i;
      int slot = c * 1024 + l * 16;
      {  // K tile: rows=k tokens (256B each), swizzle byte^=(row&7)<<4
        int row = slot >> 8;
        int inner = (slot & 255) ^ ((row & 7) << 4);
        g2l16((const char*)(Kg + (size_t)kt * 64 * 128) + row * 256 + inner,
              (char*)Kl + c * 1024);
      }
      {  // V tile: rows=d (128B each), same swizzle
        int row = slot >> 7;
        int inner = (slot & 127) ^ ((row & 7) << 4);
        g2l16((const char*)Vg + (size_t)row * 4096 + kt * 128 + inner,
              (char*)Vl + c * 1024);
      }
    }
    __syncthreads();
    // QK^T : A=Q, B=K (col = k token)
    f32x4 sf[4];
#pragma unroll
    for (int cf = 0; cf < 4; ++cf) sf[cf] = vzero;
#pragma unroll
    for (int ks = 0; ks < 4; ++ks)
#pragma unroll
      for (int cf = 0; cf < 4; ++cf) {
        int krow = cf * 16 + li;
        int off = (krow * 256 + ks * 64 + g * 16) ^ ((krow & 7) << 4);
        bf16x8 kf = *(const bf16x8*)((const char*)Kl + off);
        sf[cf] = mfma16(qf[ks], kf, sf[cf]);
      }
    if (kt == qt) {  // diagonal tile causal mask
#pragma unroll
      for (int cf = 0; cf < 4; ++cf)
#pragma unroll
        for (int j = 0; j < 4; ++j) {
          if (cf * 16 + li > wid * 16 + g * 4 + j) sf[cf][j] = -1e30f;
        }
    }
    // online softmax (scores pre-scaled via Q)
    float resc[4];
#pragma unroll
    for (int j = 0; j < 4; ++j) {
      float mx = fmaxf(fmaxf(sf[0][j], sf[1][j]), fmaxf(sf[2][j], sf[3][j]));
#pragma unroll
      for (int dl = 1; dl < 16; dl <<= 1) mx = fmaxf(mx, __shfl_xor(mx, dl));
      float nm = fmaxf(mrow[j], mx);
      resc[j] = exp2f((mrow[j] - nm) * 1.4426950408889634f);
      mrow[j] = nm;
      float rs = 0.f;
#pragma unroll
      for (int cf = 0; cf < 4; ++cf) {
        float p = exp2f((sf[cf][j] - nm) * 1.4426950408889634f);
        sf[cf][j] = p;
        rs += p;
      }
#pragma unroll
      for (int dl = 1; dl < 16; dl <<= 1) rs += __shfl_xor(rs, dl);
      lsum[j] = lsum[j] * resc[j] + rs;
    }
#pragma unroll
    for (int db = 0; db < 8; ++db)
#pragma unroll
      for (int j = 0; j < 4; ++j) o[db][j] *= resc[j];
    // P -> LDS (C/D layout in, A layout out; padded row 72 to spread banks)
#pragma unroll
    for (int cf = 0; cf < 4; ++cf)
#pragma unroll
      for (int j = 0; j < 4; ++j)
        Pl[wid][(g * 4 + j) * 72 + cf * 16 + li] = (__bf16)sf[cf][j];
    // PV : A=P, B=V^T (col = d)
#pragma unroll
    for (int ks = 0; ks < 2; ++ks) {
      bf16x8 pa = *(const bf16x8*)(&Pl[wid][li * 72 + ks * 32 + g * 8]);
#pragma unroll
      for (int db = 0; db < 8; ++db) {
        int vrow = db * 16 + li;
        int off = (vrow * 128 + ks * 64 + g * 16) ^ ((vrow & 7) << 4);
        bf16x8 vf = *(const bf16x8*)((const char*)Vl + off);
        o[db] = mfma16(pa, vf, o[db]);
      }
    }
    __syncthreads();
  }
  // epilogue: normalize, write ctx (b, s, h*128+d) bf16
  float inv[4];
#pragma unroll
  for (int j = 0; j < 4; ++j) inv[j] = 1.0f / lsum[j];
#pragma unroll
  for (int db = 0; db < 8; ++db)
#pragma unroll
    for (int j = 0; j < 4; ++j) {
      int row = q0 + wid * 16 + g * 4 + j;
      ctx[((size_t)(b * 2048) + row) * 4096 + h * 128 + db * 16 + li] = f2bf(o[db][j] * inv[j]);
    }
}

extern "C" void kernel_launch(void* const* d_in, const int* in_sizes, int n_in,
                              void* d_out, int out_size, void* d_ws, size_t ws_size,
                              hipStream_t stream) {
  (void)in_sizes; (void)n_in; (void)out_size; (void)ws_size;
  const float* X   = (const float*)d_in[0];
  const int*   mod = (const int*)d_in[1];
  const int*   pos = (const int*)d_in[2];
  const float* Wq  = (const float*)d_in[3];
  const float* Wk0 = (const float*)d_in[4];
  const float* Wk1 = (const float*)d_in[5];
  const float* Wv0 = (const float*)d_in[6];
  const float* Wv1 = (const float*)d_in[7];
  const float* Wo  = (const float*)d_in[8];
  float* out = (float*)d_out;

  u16* p = (u16*)d_ws;
  auto take = [&](size_t n) { u16* r = p; p += n; return r; };
  u16* Xb   = take(16777216);  // X bf16 (4096 x 4096)
  u16* WqT  = take(16777216);  // Wq^T (4096 x 4096)
  u16* WoT  = take(16777216);  // Wo^T
  u16* WkvT = take(16777216);  // [Wk0|Wk1|Wv0|Wv1]^T stacked (4096 x 4096)
  u16* Qr   = take(16777216);  // (b,h,s,d)
  u16* KV4  = take(16777216);  // K0r|K1r|V0r|V1r, each (b,8,s,d)
  // aliases (lifetimes disjoint, stream-ordered):
  u16* Kr  = WqT;               // roped+selected K (b,8,s,d)
  u16* Vtr = WqT + 4194304;     // selected V transposed (b,8,d,s)
  u16* ctx = Xb;                // attention out (b,s,h*128+d)

  k_cvt<<<dim3(16384), 256, 0, stream>>>(X, Xb, 4194304);
  k_tcvt<<<dim3(128, 128), 256, 0, stream>>>(Wq, WqT, 4096, 4096);
  k_tcvt<<<dim3(32, 128), 256, 0, stream>>>(Wk0, WkvT,               4096, 1024);
  k_tcvt<<<dim3(32, 128), 256, 0, stream>>>(Wk1, WkvT + 1 * 4194304, 4096, 1024);
  k_tcvt<<<dim3(32, 128), 256, 0, stream>>>(Wv0, WkvT + 2 * 4194304, 4096, 1024);
  k_tcvt<<<dim3(32, 128), 256, 0, stream>>>(Wv1, WkvT + 3 * 4194304, 4096, 1024);
  k_tcvt<<<dim3(128, 128), 256, 0, stream>>>(Wo, WoT, 4096, 4096);

  k_gemm<1><<<dim3(32, 32), 256, 0, stream>>>(Xb, WqT,  (void*)Qr,  4096, 4096, 4096, 32);
  k_gemm<3><<<dim3(32, 32), 256, 0, stream>>>(Xb, WkvT, (void*)KV4, 4096, 4096, 4096, 8);

  k_ropeq<<<dim3(32768), 256, 0, stream>>>(Qr, pos);
  k_kvprep<<<dim3(512), 256, 0, stream>>>(KV4, KV4 + 4194304, KV4 + 2 * 4194304,
                                          KV4 + 3 * 4194304, mod, pos, Kr, Vtr);

  k_attn<<<dim3(32, 64), 256, 0, stream>>>(Qr, Kr, Vtr, ctx);

  k_gemm<2><<<dim3(32, 32), 256, 0, stream>>>(ctx, WoT, (void*)out, 4096, 4096, 4096, 0);
}